// Round 10
// baseline (327.677 us; speedup 1.0000x reference)
//
#include <hip/hip_runtime.h>

typedef _Float16 f16;
typedef f16 half8 __attribute__((ext_vector_type(8)));
typedef __fp16 fp16x2 __attribute__((ext_vector_type(2)));
typedef float f32x4 __attribute__((ext_vector_type(4)));
typedef float f32x16 __attribute__((ext_vector_type(16)));

#define MFMA16(a, b, c) __builtin_amdgcn_mfma_f32_16x16x32_f16((a), (b), (c), 0, 0, 0)
#define MFMA32(a, b, c) __builtin_amdgcn_mfma_f32_32x32x16_f16((a), (b), (c), 0, 0, 0)

static constexpr int B = 8, C = 256, CI = 128, N = 6272, M = 1568, MP = 1600;

// f16-element offsets into workspace (~71 MB). Y aliases phiF (consumed by k_pool).
static constexpr size_t oXT = 0;                         // (unused since transpose fused)
static constexpr size_t oQ  = (size_t)B * N * C;         // [B][N][CI]  theta
static constexpr size_t oPF = oQ  + (size_t)B * N * CI;  // [B][N][CI]  phi full-res; later Y
static constexpr size_t oGF = oPF + (size_t)B * N * CI;  // [B][N][CI]  g full-res
static constexpr size_t oPP = oGF + (size_t)B * N * CI;  // [B][MP][CI] phi pooled (K), pad zeroed
static constexpr size_t oGT = oPP + (size_t)B * MP * CI; // [B][CI][MP] g pooled transposed (V), pad zeroed
static constexpr size_t oW  = oGT + (size_t)B * MP * CI; // 4*32768 f16 weights: theta|phi|g|W

static __device__ __forceinline__ half8 hmax8(half8 a, half8 b) {
    half8 r;
#pragma unroll
    for (int j = 0; j < 8; j++) r[j] = a[j] > b[j] ? a[j] : b[j];
    return r;
}

static __device__ __forceinline__ int pk2(float a, float b) {
    union { fp16x2 h; int i; } u;
    u.h = __builtin_amdgcn_cvt_pkrtz(a, b);
    return u.i;
}

// ---------------- weight cast fp32 -> f16 ----------------
__global__ void k_prep(const float* tw, const float* pw, const float* gw,
                       const float* Ww, f16* dst) {
    int i = blockIdx.x * 256 + threadIdx.x;   // 0..131071
    int s = i >> 15, j = i & 32767;
    float v;
    if (s == 0) v = tw[j];
    else if (s == 1) v = pw[j];
    else if (s == 2) v = gw[j];
    else v = Ww[j];
    dst[i] = (f16)v;
}

// ---------------- fused transpose + projection GEMM ----------------
// {theta,phi,g}[b][n][ci] = x[b][:][n] . w_p + bias_p.  x read in native [c][n] layout
// (coalesced), cast to f16, scattered into xs[n][c].  grid (8, 98).
__global__ __launch_bounds__(256, 2) void k_proj3(const float* __restrict__ x,
                                                  const f16* __restrict__ w16,
                                                  const float* __restrict__ tb,
                                                  const float* __restrict__ pb,
                                                  const float* __restrict__ gb,
                                                  f16* __restrict__ outQ,
                                                  f16* __restrict__ outP,
                                                  f16* __restrict__ outG) {
    __shared__ f16 xs[64 * 72];        // [64 n][64 k] pad 8
    __shared__ f16 ws[3 * 128 * 72];   // per proj: [128 ci][64 k] pad 8
    int b = blockIdx.x, n0 = blockIdx.y * 64;
    int tid = threadIdx.x, w = tid >> 6, lane = tid & 63, ln = lane & 15, quad = lane >> 4;
    f32x4 acc[3][8];
#pragma unroll
    for (int p = 0; p < 3; p++)
#pragma unroll
        for (int cb = 0; cb < 8; cb++) acc[p][cb] = (f32x4){0.f, 0.f, 0.f, 0.f};

    for (int kc = 0; kc < 4; kc++) {
#pragma unroll
        for (int i = 0; i < 16; i++) {
            int qq = tid + i * 256;            // 0..4095
            int nn = qq & 63, cc = qq >> 6;    // lanes -> consecutive n (coalesced)
            float v = x[(size_t)(b * C + kc * 64 + cc) * N + n0 + nn];
            xs[nn * 72 + cc] = (f16)v;
        }
#pragma unroll
        for (int p = 0; p < 3; p++)
#pragma unroll
            for (int i = 0; i < 4; i++) {
                int qq = tid + i * 256;        // 0..1023
                int row = qq >> 3, coff = (qq & 7) * 8;
                *(int4*)&ws[p * 9216 + row * 72 + coff] =
                    *(const int4*)&w16[(size_t)p * 32768 + (size_t)row * C + kc * 64 + coff];
            }
        __syncthreads();
#pragma unroll
        for (int ks = 0; ks < 2; ks++) {
            half8 a = *(const half8*)&xs[(w * 16 + ln) * 72 + ks * 32 + quad * 8];
#pragma unroll
            for (int p = 0; p < 3; p++)
#pragma unroll
                for (int cb = 0; cb < 8; cb++) {
                    half8 bf = *(const half8*)&ws[p * 9216 + (cb * 16 + ln) * 72 + ks * 32 + quad * 8];
                    acc[p][cb] = MFMA16(a, bf, acc[p][cb]);
                }
        }
        __syncthreads();
    }
#pragma unroll
    for (int p = 0; p < 3; p++) {
        const float* bias = (p == 0) ? tb : (p == 1) ? pb : gb;
        f16* out = (p == 0) ? outQ : (p == 1) ? outP : outG;
#pragma unroll
        for (int cb = 0; cb < 8; cb++) {
            float bv = bias[cb * 16 + ln];
#pragma unroll
            for (int r = 0; r < 4; r++) {
                int n = n0 + w * 16 + quad * 4 + r;
                out[(size_t)(b * N + n) * CI + cb * 16 + ln] = (f16)(acc[p][cb][r] + bv);
            }
        }
    }
}

// ---------------- 2x2 spatial maxpool; K as [m][ci], V as [ci][m] ----------------
// grid (8, 25): b = blockIdx.x
__global__ __launch_bounds__(256) void k_pool(const f16* __restrict__ phiF, const f16* __restrict__ gF,
                                              f16* __restrict__ phiP, f16* __restrict__ gPT) {
    __shared__ f16 gt[128 * 72];   // [128 ci][64 m] pad 8
    int b = blockIdx.x, mt = blockIdx.y;   // mt 0..24 over MP=1600
    int tid = threadIdx.x;
#pragma unroll
    for (int i = 0; i < 4; i++) {
        int qq = tid + i * 256;            // 0..1023
        int ml = qq >> 4, coff = (qq & 15) * 8;
        int m = mt * 64 + ml;
        half8 pv, gv;
        if (m < M) {
            int t = m / 196, rr = m % 196, hp = rr / 14, wp = rr % 14;
            int nb = t * 784 + hp * 56 + wp * 2;
            size_t base = ((size_t)(b * N) + nb) * CI + coff;
            half8 p0 = *(const half8*)&phiF[base];
            half8 p1 = *(const half8*)&phiF[base + CI];
            half8 p2 = *(const half8*)&phiF[base + 28 * CI];
            half8 p3 = *(const half8*)&phiF[base + 29 * CI];
            pv = hmax8(hmax8(p0, p1), hmax8(p2, p3));
            half8 g0 = *(const half8*)&gF[base];
            half8 g1 = *(const half8*)&gF[base + CI];
            half8 g2 = *(const half8*)&gF[base + 28 * CI];
            half8 g3 = *(const half8*)&gF[base + 29 * CI];
            gv = hmax8(hmax8(g0, g1), hmax8(g2, g3));
        } else {
#pragma unroll
            for (int j = 0; j < 8; j++) { pv[j] = (f16)0.f; gv[j] = (f16)0.f; }
        }
        *(half8*)&phiP[((size_t)b * MP + m) * CI + coff] = pv;
#pragma unroll
        for (int j = 0; j < 8; j++) gt[(coff + j) * 72 + ml] = gv[j];
    }
    __syncthreads();
#pragma unroll
    for (int i = 0; i < 4; i++) {
        int qq = tid + i * 256;
        int ci = qq >> 3, moff = (qq & 7) * 8;
        *(int4*)&gPT[((size_t)(b * CI) + ci) * MP + mt * 64 + moff] = *(const int4*)&gt[ci * 72 + moff];
    }
}

// ---------------- flash attention: y[b][n][ci] ----------------
// v7: 8 waves (512 thr); wave-groups 0/1 split each 64-m chunk in half (group g owns m rows
//     g*32+l31).  v5 memory structure (reg-staged int4, XOR-swz K, pad-72 V, 0 conflicts),
//     ONE shared K/V tile per iter -> per-wave chain halved, waves/SIMD doubled.
//     End: group1 exports O/Osum (f16) + (mi,Osum) into dead stage LDS; group0 combines
//     (two-way online softmax merge) and writes y.  All barriers unconditional.
__global__ __launch_bounds__(512, 4) void k_attn(const f16* __restrict__ q,
                                                 const f16* __restrict__ kk,
                                                 const f16* __restrict__ v,
                                                 f16* __restrict__ y) {
    __shared__ f16 smem[17408];      // Ks: [64 m][128 d] swz (8192) | Vs: [128 ci][72 pad] (9216)
    f16* Ks = smem;
    f16* Vs = smem + 8192;
    int b = blockIdx.x, n0 = blockIdx.y * 128;
    int tid = threadIdx.x, w = tid >> 6, lane = tid & 63;
    int l31 = lane & 31, hi = lane >> 5;
    int grp = w >> 2, wl = w & 3;
    int wq = n0 + wl * 32;
    int mrow = grp * 32 + l31;       // this wave's K row / m-offset within a chunk

    // Q fragments (B-operand: col=lane&31=q, k=8*hi+j), pre-scaled by log2(e)
    half8 qf[8];
#pragma unroll
    for (int kc = 0; kc < 8; kc++) {
        qf[kc] = *(const half8*)&q[(size_t)(b * N + wq + l31) * CI + kc * 16 + hi * 8];
#pragma unroll
        for (int j = 0; j < 8; j++) qf[kc][j] *= (f16)1.4426950408889634f;
    }

    f32x16 O0, O1, O2, O3;
#pragma unroll
    for (int i = 0; i < 16; i++) { O0[i] = 0.f; O1[i] = 0.f; O2[i] = 0.f; O3[i] = 0.f; }
    float Osum = 0.f, mi = -1e30f;

    for (int mc = 0; mc < 25; mc++) {
        // ---- stage K (16KB, swizzled) + V (16KB, pad-72): 512 threads, 2 int4 each ----
#pragma unroll
        for (int i = 0; i < 2; i++) {
            int qq = tid + i * 512;
            int kr = qq >> 4, c16 = qq & 15;
            *(int4*)&Ks[kr * 128 + ((c16 ^ (kr & 15)) << 3)] =
                *(const int4*)&kk[((size_t)b * MP + mc * 64 + kr) * CI + c16 * 8];
            int vr = qq >> 3, vc = (qq & 7) * 8;
            *(int4*)&Vs[vr * 72 + vc] = *(const int4*)&v[((size_t)(b * CI) + vr) * MP + mc * 64 + vc];
        }
        __syncthreads();

        // ---- QK^T (half-chunk): S[m_local 0..31][q], 8 MFMA32 ----
        f32x16 S;
#pragma unroll
        for (int i = 0; i < 16; i++) S[i] = 0.f;
        __builtin_amdgcn_s_setprio(1);
#pragma unroll
        for (int kc = 0; kc < 8; kc++) {
            int c16 = kc * 2 + hi;
            half8 a = *(const half8*)&Ks[mrow * 128 + ((c16 ^ (mrow & 15)) << 3)];
            S = MFMA32(a, qf[kc], S);
        }
        __builtin_amdgcn_s_setprio(0);

        // ---- in-register online softmax (log2 domain). q = lane&31 ----
        float vm = S[0];
#pragma unroll
        for (int i = 1; i < 16; i++) vm = fmaxf(vm, S[i]);
        vm = fmaxf(vm, __shfl_xor(vm, 32));
        if (__ballot(vm > mi + 8.f)) {              // defer-rescale; wave-uniform
            float mnew = fmaxf(mi, vm);
            float alpha = __builtin_amdgcn_exp2f(mi - mnew);
            mi = mnew;
            Osum *= alpha;
#pragma unroll
            for (int r = 0; r < 16; r++) {
                int qr = (r & 3) + 8 * (r >> 2) + 4 * hi;
                float al = __shfl(alpha, qr);
                O0[r] *= al; O1[r] *= al; O2[r] *= al; O3[r] *= al;
            }
        }
#pragma unroll
        for (int i = 0; i < 16; i++) S[i] = __builtin_amdgcn_exp2f(S[i] - mi);
        if (mc == 24 && grp) {                      // m 1568..1599 = group1's slice of chunk 24
#pragma unroll
            for (int i = 0; i < 16; i++) S[i] = 0.f;
        }
        float ts = 0.f;
#pragma unroll
        for (int i = 0; i < 16; i++) ts += S[i];
        ts += __shfl_xor(ts, 32);
        Osum += ts;

        // ---- P -> A-fragments (cvt_pk + half-swap + select), PV: 8 MFMA32 ----
        __builtin_amdgcn_s_setprio(1);
#define PV_CHUNK(SV, RB, KC)                                                                   \
        {                                                                                      \
            int a0 = pk2(SV[RB + 0], SV[RB + 1]);                                              \
            int a1 = pk2(SV[RB + 2], SV[RB + 3]);                                              \
            int a2 = pk2(SV[RB + 4], SV[RB + 5]);                                              \
            int a3 = pk2(SV[RB + 6], SV[RB + 7]);                                              \
            int b0 = __shfl_xor(a0, 32), b1 = __shfl_xor(a1, 32);                              \
            int b2 = __shfl_xor(a2, 32), b3 = __shfl_xor(a3, 32);                              \
            union { int4 i4; half8 h8; } u;                                                    \
            u.i4.x = hi ? b2 : a0; u.i4.y = hi ? b3 : a1;                                      \
            u.i4.z = hi ? a2 : b0; u.i4.w = hi ? a3 : b1;                                      \
            O0 = MFMA32(u.h8, *(const half8*)&Vs[(0 * 32 + l31) * 72 + (KC) * 16 + hi * 8], O0); \
            O1 = MFMA32(u.h8, *(const half8*)&Vs[(1 * 32 + l31) * 72 + (KC) * 16 + hi * 8], O1); \
            O2 = MFMA32(u.h8, *(const half8*)&Vs[(2 * 32 + l31) * 72 + (KC) * 16 + hi * 8], O2); \
            O3 = MFMA32(u.h8, *(const half8*)&Vs[(3 * 32 + l31) * 72 + (KC) * 16 + hi * 8], O3); \
        }
        PV_CHUNK(S, 0, 2 * grp)
        PV_CHUNK(S, 8, 2 * grp + 1)
#undef PV_CHUNK
        __builtin_amdgcn_s_setprio(0);
        __syncthreads();
    }

    // ---- combine: group1 exports normalized O (f16) + (mi, Osum) into dead stage LDS ----
    f16* OB = smem;                        // [128 q][128 ci] f16 = 32KB
    float* mB = (float*)(smem + 16384);    // [128]
    float* sB = mB + 128;                  // [128]
    if (grp == 1) {
#pragma unroll
        for (int r = 0; r < 16; r++) {
            int qr = (r & 3) + 8 * (r >> 2) + 4 * hi;
            float is = 1.0f / __shfl(Osum, qr);
            int qloc = wl * 32 + qr;
            OB[qloc * 128 + l31]      = (f16)(O0[r] * is);
            OB[qloc * 128 + 32 + l31] = (f16)(O1[r] * is);
            OB[qloc * 128 + 64 + l31] = (f16)(O2[r] * is);
            OB[qloc * 128 + 96 + l31] = (f16)(O3[r] * is);
        }
        mB[wl * 32 + l31] = mi;     // per q = l31 (dup across hi benign)
        sB[wl * 32 + l31] = Osum;
    }
    __syncthreads();
    if (grp == 0) {
#pragma unroll
        for (int r = 0; r < 16; r++) {
            int qr = (r & 3) + 8 * (r >> 2) + 4 * hi;
            int qloc = wl * 32 + qr;
            float mA = __shfl(mi, qr), sA = __shfl(Osum, qr);
            float mBq = mB[qloc], sBq = sB[qloc];
            float m = fmaxf(mA, mBq);
            float al = __builtin_amdgcn_exp2f(mA - m);
            float be = __builtin_amdgcn_exp2f(mBq - m);
            float denom = sA * al + sBq * be;
            float cA = al / denom, cB = sBq * be / denom;
            size_t base = (size_t)(b * N + wq + qr) * CI + l31;
            y[base]      = (f16)(O0[r] * cA + (float)OB[qloc * 128 + l31] * cB);
            y[base + 32] = (f16)(O1[r] * cA + (float)OB[qloc * 128 + 32 + l31] * cB);
            y[base + 64] = (f16)(O2[r] * cA + (float)OB[qloc * 128 + 64 + l31] * cB);
            y[base + 96] = (f16)(O3[r] * cA + (float)OB[qloc * 128 + 96 + l31] * cB);
        }
    }
}

// ---------------- final: out[b][c][n] = W.y + Wb + x ----------------
// grid (8, 98, 2): b = blockIdx.x, n-tile = blockIdx.y, c-half = blockIdx.z
__global__ __launch_bounds__(256) void k_final(const f16* __restrict__ y,
                                               const f16* __restrict__ Ww,
                                               const float* __restrict__ Wb,
                                               const float* __restrict__ x,
                                               float* __restrict__ out) {
    __shared__ f16 ys[64 * 136];    // [64 n][128 ci] pad 8
    __shared__ f16 Ws[128 * 136];   // [128 c][128 ci] pad 8
    int b = blockIdx.x, ch = blockIdx.z, n0 = blockIdx.y * 64;
    int tid = threadIdx.x, w = tid >> 6, lane = tid & 63, ln = lane & 15, quad = lane >> 4;
#pragma unroll
    for (int i = 0; i < 4; i++) {
        int qq = tid + i * 256; int row = qq >> 4, coff = (qq & 15) * 8;
        *(int4*)&ys[row * 136 + coff] =
            *(const int4*)&y[(size_t)(b * N + n0 + row) * CI + coff];
    }
#pragma unroll
    for (int i = 0; i < 8; i++) {
        int qq = tid + i * 256; int row = qq >> 4, coff = (qq & 15) * 8;
        *(int4*)&Ws[row * 136 + coff] =
            *(const int4*)&Ww[(size_t)(ch * 128 + row) * CI + coff];
    }
    __syncthreads();
    f32x4 acc[2][4];
#pragma unroll
    for (int rb = 0; rb < 2; rb++)
#pragma unroll
        for (int nb = 0; nb < 4; nb++) acc[rb][nb] = (f32x4){0.f, 0.f, 0.f, 0.f};
#pragma unroll
    for (int ks = 0; ks < 4; ks++) {
        half8 a0 = *(const half8*)&Ws[(w * 32 + ln) * 136 + ks * 32 + quad * 8];
        half8 a1 = *(const half8*)&Ws[(w * 32 + 16 + ln) * 136 + ks * 32 + quad * 8];
#pragma unroll
        for (int nb = 0; nb < 4; nb++) {
            half8 bf = *(const half8*)&ys[(nb * 16 + ln) * 136 + ks * 32 + quad * 8];
            acc[0][nb] = MFMA16(a0, bf, acc[0][nb]);
            acc[1][nb] = MFMA16(a1, bf, acc[1][nb]);
        }
    }
#pragma unroll
    for (int rb = 0; rb < 2; rb++) {
        int cbase = ch * 128 + w * 32 + rb * 16 + quad * 4;
#pragma unroll
        for (int nb = 0; nb < 4; nb++) {
#pragma unroll
            for (int r = 0; r < 4; r++) {
                int c = cbase + r;
                size_t addr = (size_t)(b * C + c) * N + n0 + nb * 16 + ln;
                out[addr] = acc[rb][nb][r] + Wb[c] + x[addr];
            }
        }
    }
}

extern "C" void kernel_launch(void* const* d_in, const int* in_sizes, int n_in,
                              void* d_out, int out_size, void* d_ws, size_t ws_size,
                              hipStream_t stream) {
    const float* x  = (const float*)d_in[0];
    const float* gw = (const float*)d_in[1];
    const float* gb = (const float*)d_in[2];
    const float* tw = (const float*)d_in[3];
    const float* tb = (const float*)d_in[4];
    const float* pw = (const float*)d_in[5];
    const float* pb = (const float*)d_in[6];
    const float* Ww = (const float*)d_in[7];
    const float* Wb = (const float*)d_in[8];
    float* out = (float*)d_out;
    f16* ws = (f16*)d_ws;

    f16* Q    = ws + oQ;
    f16* phiF = ws + oPF;
    f16* gF   = ws + oGF;
    f16* phiP = ws + oPP;
    f16* gPT  = ws + oGT;
    f16* Y    = ws + oPF;   // alias: phiF dead after k_pool
    f16* w16  = ws + oW;

    k_prep<<<512, 256, 0, stream>>>(tw, pw, gw, Ww, w16);
    k_proj3<<<dim3(8, 98), 256, 0, stream>>>(x, w16, tb, pb, gb, Q, phiF, gF);
    k_pool<<<dim3(8, 25), 256, 0, stream>>>(phiF, gF, phiP, gPT);
    k_attn<<<dim3(8, 49), 512, 0, stream>>>(Q, phiP, gPT, Y);
    k_final<<<dim3(8, 98, 2), 256, 0, stream>>>(Y, w16 + 98304, Wb, x, out);
    (void)in_sizes; (void)n_in; (void)out_size; (void)ws_size;
}

// Round 11
// 250.451 us; speedup vs baseline: 1.3083x; 1.3083x over previous
//
#include <hip/hip_runtime.h>

typedef _Float16 f16;
typedef f16 half8 __attribute__((ext_vector_type(8)));
typedef __fp16 fp16x2 __attribute__((ext_vector_type(2)));
typedef float f32x4 __attribute__((ext_vector_type(4)));
typedef float f32x16 __attribute__((ext_vector_type(16)));

#define MFMA16(a, b, c) __builtin_amdgcn_mfma_f32_16x16x32_f16((a), (b), (c), 0, 0, 0)
#define MFMA32(a, b, c) __builtin_amdgcn_mfma_f32_32x32x16_f16((a), (b), (c), 0, 0, 0)

static constexpr int B = 8, C = 256, CI = 128, N = 6272, M = 1568, MP = 1600;

// f16-element offsets into workspace (~71 MB). Y aliases phiF (consumed by k_pool).
static constexpr size_t oXT = 0;                         // (unused since transpose fused)
static constexpr size_t oQ  = (size_t)B * N * C;         // [B][N][CI]  theta
static constexpr size_t oPF = oQ  + (size_t)B * N * CI;  // [B][N][CI]  phi full-res; later Y
static constexpr size_t oGF = oPF + (size_t)B * N * CI;  // [B][N][CI]  g full-res
static constexpr size_t oPP = oGF + (size_t)B * N * CI;  // [B][MP][CI] phi pooled (K), pad zeroed
static constexpr size_t oGT = oPP + (size_t)B * MP * CI; // [B][CI][MP] g pooled transposed (V), pad zeroed
static constexpr size_t oW  = oGT + (size_t)B * MP * CI; // 4*32768 f16 weights: theta|phi|g|W

static __device__ __forceinline__ half8 hmax8(half8 a, half8 b) {
    half8 r;
#pragma unroll
    for (int j = 0; j < 8; j++) r[j] = a[j] > b[j] ? a[j] : b[j];
    return r;
}

static __device__ __forceinline__ int pk2(float a, float b) {
    union { fp16x2 h; int i; } u;
    u.h = __builtin_amdgcn_cvt_pkrtz(a, b);
    return u.i;
}

// ---------------- weight cast fp32 -> f16 ----------------
__global__ void k_prep(const float* tw, const float* pw, const float* gw,
                       const float* Ww, f16* dst) {
    int i = blockIdx.x * 256 + threadIdx.x;   // 0..131071
    int s = i >> 15, j = i & 32767;
    float v;
    if (s == 0) v = tw[j];
    else if (s == 1) v = pw[j];
    else if (s == 2) v = gw[j];
    else v = Ww[j];
    dst[i] = (f16)v;
}

// ---------------- fused transpose + projection GEMM ----------------
// {theta,phi,g}[b][n][ci] = x[b][:][n] . w_p + bias_p.  x read in native [c][n] layout
// (coalesced), cast to f16, scattered into xs[n][c].  grid (8, 98).
__global__ __launch_bounds__(256, 2) void k_proj3(const float* __restrict__ x,
                                                  const f16* __restrict__ w16,
                                                  const float* __restrict__ tb,
                                                  const float* __restrict__ pb,
                                                  const float* __restrict__ gb,
                                                  f16* __restrict__ outQ,
                                                  f16* __restrict__ outP,
                                                  f16* __restrict__ outG) {
    __shared__ f16 xs[64 * 72];        // [64 n][64 k] pad 8
    __shared__ f16 ws[3 * 128 * 72];   // per proj: [128 ci][64 k] pad 8
    int b = blockIdx.x, n0 = blockIdx.y * 64;
    int tid = threadIdx.x, w = tid >> 6, lane = tid & 63, ln = lane & 15, quad = lane >> 4;
    f32x4 acc[3][8];
#pragma unroll
    for (int p = 0; p < 3; p++)
#pragma unroll
        for (int cb = 0; cb < 8; cb++) acc[p][cb] = (f32x4){0.f, 0.f, 0.f, 0.f};

    for (int kc = 0; kc < 4; kc++) {
#pragma unroll
        for (int i = 0; i < 16; i++) {
            int qq = tid + i * 256;            // 0..4095
            int nn = qq & 63, cc = qq >> 6;    // lanes -> consecutive n (coalesced)
            float v = x[(size_t)(b * C + kc * 64 + cc) * N + n0 + nn];
            xs[nn * 72 + cc] = (f16)v;
        }
#pragma unroll
        for (int p = 0; p < 3; p++)
#pragma unroll
            for (int i = 0; i < 4; i++) {
                int qq = tid + i * 256;        // 0..1023
                int row = qq >> 3, coff = (qq & 7) * 8;
                *(int4*)&ws[p * 9216 + row * 72 + coff] =
                    *(const int4*)&w16[(size_t)p * 32768 + (size_t)row * C + kc * 64 + coff];
            }
        __syncthreads();
#pragma unroll
        for (int ks = 0; ks < 2; ks++) {
            half8 a = *(const half8*)&xs[(w * 16 + ln) * 72 + ks * 32 + quad * 8];
#pragma unroll
            for (int p = 0; p < 3; p++)
#pragma unroll
                for (int cb = 0; cb < 8; cb++) {
                    half8 bf = *(const half8*)&ws[p * 9216 + (cb * 16 + ln) * 72 + ks * 32 + quad * 8];
                    acc[p][cb] = MFMA16(a, bf, acc[p][cb]);
                }
        }
        __syncthreads();
    }
#pragma unroll
    for (int p = 0; p < 3; p++) {
        const float* bias = (p == 0) ? tb : (p == 1) ? pb : gb;
        f16* out = (p == 0) ? outQ : (p == 1) ? outP : outG;
#pragma unroll
        for (int cb = 0; cb < 8; cb++) {
            float bv = bias[cb * 16 + ln];
#pragma unroll
            for (int r = 0; r < 4; r++) {
                int n = n0 + w * 16 + quad * 4 + r;
                out[(size_t)(b * N + n) * CI + cb * 16 + ln] = (f16)(acc[p][cb][r] + bv);
            }
        }
    }
}

// ---------------- 2x2 spatial maxpool; K as [m][ci], V as [ci][m] ----------------
// grid (8, 25): b = blockIdx.x
__global__ __launch_bounds__(256) void k_pool(const f16* __restrict__ phiF, const f16* __restrict__ gF,
                                              f16* __restrict__ phiP, f16* __restrict__ gPT) {
    __shared__ f16 gt[128 * 72];   // [128 ci][64 m] pad 8
    int b = blockIdx.x, mt = blockIdx.y;   // mt 0..24 over MP=1600
    int tid = threadIdx.x;
#pragma unroll
    for (int i = 0; i < 4; i++) {
        int qq = tid + i * 256;            // 0..1023
        int ml = qq >> 4, coff = (qq & 15) * 8;
        int m = mt * 64 + ml;
        half8 pv, gv;
        if (m < M) {
            int t = m / 196, rr = m % 196, hp = rr / 14, wp = rr % 14;
            int nb = t * 784 + hp * 56 + wp * 2;
            size_t base = ((size_t)(b * N) + nb) * CI + coff;
            half8 p0 = *(const half8*)&phiF[base];
            half8 p1 = *(const half8*)&phiF[base + CI];
            half8 p2 = *(const half8*)&phiF[base + 28 * CI];
            half8 p3 = *(const half8*)&phiF[base + 29 * CI];
            pv = hmax8(hmax8(p0, p1), hmax8(p2, p3));
            half8 g0 = *(const half8*)&gF[base];
            half8 g1 = *(const half8*)&gF[base + CI];
            half8 g2 = *(const half8*)&gF[base + 28 * CI];
            half8 g3 = *(const half8*)&gF[base + 29 * CI];
            gv = hmax8(hmax8(g0, g1), hmax8(g2, g3));
        } else {
#pragma unroll
            for (int j = 0; j < 8; j++) { pv[j] = (f16)0.f; gv[j] = (f16)0.f; }
        }
        *(half8*)&phiP[((size_t)b * MP + m) * CI + coff] = pv;
#pragma unroll
        for (int j = 0; j < 8; j++) gt[(coff + j) * 72 + ml] = gv[j];
    }
    __syncthreads();
#pragma unroll
    for (int i = 0; i < 4; i++) {
        int qq = tid + i * 256;
        int ci = qq >> 3, moff = (qq & 7) * 8;
        *(int4*)&gPT[((size_t)(b * CI) + ci) * MP + mt * 64 + moff] = *(const int4*)&gt[ci * 72 + moff];
    }
}

// ---------------- flash attention: y[b][n][ci] ----------------
// v8 = v7 with launch_bounds(512, 2): v7's (512, 4) forced VGPR=64 -> full scratch spill
//     (WRITE 58.8MB, 181us).  (512, 2) lets the allocator take its natural ~108 regs;
//     2 blocks/CU remain reachable via LDS/VGPR.  Split-m combine logic unchanged
//     (verified correct in round 10: passed, absmax 0.03125).
__global__ __launch_bounds__(512, 2) void k_attn(const f16* __restrict__ q,
                                                 const f16* __restrict__ kk,
                                                 const f16* __restrict__ v,
                                                 f16* __restrict__ y) {
    __shared__ f16 smem[17408];      // Ks: [64 m][128 d] swz (8192) | Vs: [128 ci][72 pad] (9216)
    f16* Ks = smem;
    f16* Vs = smem + 8192;
    int b = blockIdx.x, n0 = blockIdx.y * 128;
    int tid = threadIdx.x, w = tid >> 6, lane = tid & 63;
    int l31 = lane & 31, hi = lane >> 5;
    int grp = w >> 2, wl = w & 3;
    int wq = n0 + wl * 32;
    int mrow = grp * 32 + l31;       // this wave's K row / m-offset within a chunk

    // Q fragments (B-operand: col=lane&31=q, k=8*hi+j), pre-scaled by log2(e)
    half8 qf[8];
#pragma unroll
    for (int kc = 0; kc < 8; kc++) {
        qf[kc] = *(const half8*)&q[(size_t)(b * N + wq + l31) * CI + kc * 16 + hi * 8];
#pragma unroll
        for (int j = 0; j < 8; j++) qf[kc][j] *= (f16)1.4426950408889634f;
    }

    f32x16 O0, O1, O2, O3;
#pragma unroll
    for (int i = 0; i < 16; i++) { O0[i] = 0.f; O1[i] = 0.f; O2[i] = 0.f; O3[i] = 0.f; }
    float Osum = 0.f, mi = -1e30f;

    for (int mc = 0; mc < 25; mc++) {
        // ---- stage K (16KB, swizzled) + V (16KB, pad-72): 512 threads, 2 int4 each ----
#pragma unroll
        for (int i = 0; i < 2; i++) {
            int qq = tid + i * 512;
            int kr = qq >> 4, c16 = qq & 15;
            *(int4*)&Ks[kr * 128 + ((c16 ^ (kr & 15)) << 3)] =
                *(const int4*)&kk[((size_t)b * MP + mc * 64 + kr) * CI + c16 * 8];
            int vr = qq >> 3, vc = (qq & 7) * 8;
            *(int4*)&Vs[vr * 72 + vc] = *(const int4*)&v[((size_t)(b * CI) + vr) * MP + mc * 64 + vc];
        }
        __syncthreads();

        // ---- QK^T (half-chunk): S[m_local 0..31][q], 8 MFMA32 ----
        f32x16 S;
#pragma unroll
        for (int i = 0; i < 16; i++) S[i] = 0.f;
        __builtin_amdgcn_s_setprio(1);
#pragma unroll
        for (int kc = 0; kc < 8; kc++) {
            int c16 = kc * 2 + hi;
            half8 a = *(const half8*)&Ks[mrow * 128 + ((c16 ^ (mrow & 15)) << 3)];
            S = MFMA32(a, qf[kc], S);
        }
        __builtin_amdgcn_s_setprio(0);

        // ---- in-register online softmax (log2 domain). q = lane&31 ----
        float vm = S[0];
#pragma unroll
        for (int i = 1; i < 16; i++) vm = fmaxf(vm, S[i]);
        vm = fmaxf(vm, __shfl_xor(vm, 32));
        if (__ballot(vm > mi + 8.f)) {              // defer-rescale; wave-uniform
            float mnew = fmaxf(mi, vm);
            float alpha = __builtin_amdgcn_exp2f(mi - mnew);
            mi = mnew;
            Osum *= alpha;
#pragma unroll
            for (int r = 0; r < 16; r++) {
                int qr = (r & 3) + 8 * (r >> 2) + 4 * hi;
                float al = __shfl(alpha, qr);
                O0[r] *= al; O1[r] *= al; O2[r] *= al; O3[r] *= al;
            }
        }
#pragma unroll
        for (int i = 0; i < 16; i++) S[i] = __builtin_amdgcn_exp2f(S[i] - mi);
        if (mc == 24 && grp) {                      // m 1568..1599 = group1's slice of chunk 24
#pragma unroll
            for (int i = 0; i < 16; i++) S[i] = 0.f;
        }
        float ts = 0.f;
#pragma unroll
        for (int i = 0; i < 16; i++) ts += S[i];
        ts += __shfl_xor(ts, 32);
        Osum += ts;

        // ---- P -> A-fragments (cvt_pk + half-swap + select), PV: 8 MFMA32 ----
        __builtin_amdgcn_s_setprio(1);
#define PV_CHUNK(SV, RB, KC)                                                                   \
        {                                                                                      \
            int a0 = pk2(SV[RB + 0], SV[RB + 1]);                                              \
            int a1 = pk2(SV[RB + 2], SV[RB + 3]);                                              \
            int a2 = pk2(SV[RB + 4], SV[RB + 5]);                                              \
            int a3 = pk2(SV[RB + 6], SV[RB + 7]);                                              \
            int b0 = __shfl_xor(a0, 32), b1 = __shfl_xor(a1, 32);                              \
            int b2 = __shfl_xor(a2, 32), b3 = __shfl_xor(a3, 32);                              \
            union { int4 i4; half8 h8; } u;                                                    \
            u.i4.x = hi ? b2 : a0; u.i4.y = hi ? b3 : a1;                                      \
            u.i4.z = hi ? a2 : b0; u.i4.w = hi ? a3 : b1;                                      \
            O0 = MFMA32(u.h8, *(const half8*)&Vs[(0 * 32 + l31) * 72 + (KC) * 16 + hi * 8], O0); \
            O1 = MFMA32(u.h8, *(const half8*)&Vs[(1 * 32 + l31) * 72 + (KC) * 16 + hi * 8], O1); \
            O2 = MFMA32(u.h8, *(const half8*)&Vs[(2 * 32 + l31) * 72 + (KC) * 16 + hi * 8], O2); \
            O3 = MFMA32(u.h8, *(const half8*)&Vs[(3 * 32 + l31) * 72 + (KC) * 16 + hi * 8], O3); \
        }
        PV_CHUNK(S, 0, 2 * grp)
        PV_CHUNK(S, 8, 2 * grp + 1)
#undef PV_CHUNK
        __builtin_amdgcn_s_setprio(0);
        __syncthreads();
    }

    // ---- combine: group1 exports normalized O (f16) + (mi, Osum) into dead stage LDS ----
    f16* OB = smem;                        // [128 q][128 ci] f16 = 32KB
    float* mB = (float*)(smem + 16384);    // [128]
    float* sB = mB + 128;                  // [128]
    if (grp == 1) {
#pragma unroll
        for (int r = 0; r < 16; r++) {
            int qr = (r & 3) + 8 * (r >> 2) + 4 * hi;
            float is = 1.0f / __shfl(Osum, qr);
            int qloc = wl * 32 + qr;
            OB[qloc * 128 + l31]      = (f16)(O0[r] * is);
            OB[qloc * 128 + 32 + l31] = (f16)(O1[r] * is);
            OB[qloc * 128 + 64 + l31] = (f16)(O2[r] * is);
            OB[qloc * 128 + 96 + l31] = (f16)(O3[r] * is);
        }
        mB[wl * 32 + l31] = mi;     // per q = l31 (dup across hi benign)
        sB[wl * 32 + l31] = Osum;
    }
    __syncthreads();
    if (grp == 0) {
#pragma unroll
        for (int r = 0; r < 16; r++) {
            int qr = (r & 3) + 8 * (r >> 2) + 4 * hi;
            int qloc = wl * 32 + qr;
            float mA = __shfl(mi, qr), sA = __shfl(Osum, qr);
            float mBq = mB[qloc], sBq = sB[qloc];
            float m = fmaxf(mA, mBq);
            float al = __builtin_amdgcn_exp2f(mA - m);
            float be = __builtin_amdgcn_exp2f(mBq - m);
            float denom = sA * al + sBq * be;
            float cA = al / denom, cB = sBq * be / denom;
            size_t base = (size_t)(b * N + wq + qr) * CI + l31;
            y[base]      = (f16)(O0[r] * cA + (float)OB[qloc * 128 + l31] * cB);
            y[base + 32] = (f16)(O1[r] * cA + (float)OB[qloc * 128 + 32 + l31] * cB);
            y[base + 64] = (f16)(O2[r] * cA + (float)OB[qloc * 128 + 64 + l31] * cB);
            y[base + 96] = (f16)(O3[r] * cA + (float)OB[qloc * 128 + 96 + l31] * cB);
        }
    }
}

// ---------------- final: out[b][c][n] = W.y + Wb + x ----------------
// grid (8, 98, 2): b = blockIdx.x, n-tile = blockIdx.y, c-half = blockIdx.z
__global__ __launch_bounds__(256) void k_final(const f16* __restrict__ y,
                                               const f16* __restrict__ Ww,
                                               const float* __restrict__ Wb,
                                               const float* __restrict__ x,
                                               float* __restrict__ out) {
    __shared__ f16 ys[64 * 136];    // [64 n][128 ci] pad 8
    __shared__ f16 Ws[128 * 136];   // [128 c][128 ci] pad 8
    int b = blockIdx.x, ch = blockIdx.z, n0 = blockIdx.y * 64;
    int tid = threadIdx.x, w = tid >> 6, lane = tid & 63, ln = lane & 15, quad = lane >> 4;
#pragma unroll
    for (int i = 0; i < 4; i++) {
        int qq = tid + i * 256; int row = qq >> 4, coff = (qq & 15) * 8;
        *(int4*)&ys[row * 136 + coff] =
            *(const int4*)&y[(size_t)(b * N + n0 + row) * CI + coff];
    }
#pragma unroll
    for (int i = 0; i < 8; i++) {
        int qq = tid + i * 256; int row = qq >> 4, coff = (qq & 15) * 8;
        *(int4*)&Ws[row * 136 + coff] =
            *(const int4*)&Ww[(size_t)(ch * 128 + row) * CI + coff];
    }
    __syncthreads();
    f32x4 acc[2][4];
#pragma unroll
    for (int rb = 0; rb < 2; rb++)
#pragma unroll
        for (int nb = 0; nb < 4; nb++) acc[rb][nb] = (f32x4){0.f, 0.f, 0.f, 0.f};
#pragma unroll
    for (int ks = 0; ks < 4; ks++) {
        half8 a0 = *(const half8*)&Ws[(w * 32 + ln) * 136 + ks * 32 + quad * 8];
        half8 a1 = *(const half8*)&Ws[(w * 32 + 16 + ln) * 136 + ks * 32 + quad * 8];
#pragma unroll
        for (int nb = 0; nb < 4; nb++) {
            half8 bf = *(const half8*)&ys[(nb * 16 + ln) * 136 + ks * 32 + quad * 8];
            acc[0][nb] = MFMA16(a0, bf, acc[0][nb]);
            acc[1][nb] = MFMA16(a1, bf, acc[1][nb]);
        }
    }
#pragma unroll
    for (int rb = 0; rb < 2; rb++) {
        int cbase = ch * 128 + w * 32 + rb * 16 + quad * 4;
#pragma unroll
        for (int nb = 0; nb < 4; nb++) {
#pragma unroll
            for (int r = 0; r < 4; r++) {
                int c = cbase + r;
                size_t addr = (size_t)(b * C + c) * N + n0 + nb * 16 + ln;
                out[addr] = acc[rb][nb][r] + Wb[c] + x[addr];
            }
        }
    }
}

extern "C" void kernel_launch(void* const* d_in, const int* in_sizes, int n_in,
                              void* d_out, int out_size, void* d_ws, size_t ws_size,
                              hipStream_t stream) {
    const float* x  = (const float*)d_in[0];
    const float* gw = (const float*)d_in[1];
    const float* gb = (const float*)d_in[2];
    const float* tw = (const float*)d_in[3];
    const float* tb = (const float*)d_in[4];
    const float* pw = (const float*)d_in[5];
    const float* pb = (const float*)d_in[6];
    const float* Ww = (const float*)d_in[7];
    const float* Wb = (const float*)d_in[8];
    float* out = (float*)d_out;
    f16* ws = (f16*)d_ws;

    f16* Q    = ws + oQ;
    f16* phiF = ws + oPF;
    f16* gF   = ws + oGF;
    f16* phiP = ws + oPP;
    f16* gPT  = ws + oGT;
    f16* Y    = ws + oPF;   // alias: phiF dead after k_pool
    f16* w16  = ws + oW;

    k_prep<<<512, 256, 0, stream>>>(tw, pw, gw, Ww, w16);
    k_proj3<<<dim3(8, 98), 256, 0, stream>>>(x, w16, tb, pb, gb, Q, phiF, gF);
    k_pool<<<dim3(8, 25), 256, 0, stream>>>(phiF, gF, phiP, gPT);
    k_attn<<<dim3(8, 49), 512, 0, stream>>>(Q, phiP, gPT, Y);
    k_final<<<dim3(8, 98, 2), 256, 0, stream>>>(Y, w16 + 98304, Wb, x, out);
    (void)in_sizes; (void)n_in; (void)out_size; (void)ws_size;
}